// Round 1
// baseline (629.759 us; speedup 1.0000x reference)
//
#include <hip/hip_runtime.h>
#include <stdint.h>

// ContraNorm = 1.1*x - 0.1 * softmax(xn @ xn^T) @ x   (xn = row-L2-normalized x)
// Flash-attention-style fusion, bf16 MFMA, fp32 softmax/accum.
// N=16384, D=256.

typedef __bf16 bf16x8 __attribute__((ext_vector_type(8)));
typedef float f32x4 __attribute__((ext_vector_type(4)));
typedef unsigned short u16;
typedef unsigned int u32;

#define GLBP __attribute__((address_space(1)))
#define LDSP __attribute__((address_space(3)))

#define NROW 16384
#define DIMD 256

__device__ __forceinline__ void g2l16(const void* g, void* l) {
  __builtin_amdgcn_global_load_lds((const GLBP u32*)g, (LDSP u32*)l, 16, 0, 0);
}

__device__ __forceinline__ u16 f2b(float f) {
  union { __bf16 h; u16 u; } cv;
  cv.h = (__bf16)f;
  return cv.u;
}

// ---------------------------------------------------------------------------
// Prep 1: row L2-norm -> xn (bf16), stored tiled [kb=row/32][32 rows][512B row]
// with granule swizzle: granule g (16B, d = g*8..+7) stored at g ^ (r&7).
// One wave per row.
__global__ void cn_norm(const float* __restrict__ x, unsigned char* __restrict__ xn) {
  const int w = threadIdx.x >> 6, l = threadIdx.x & 63;
  const int row = blockIdx.x * 4 + w;
  const float4 v = *(const float4*)(x + row * DIMD + l * 4);
  float s = v.x * v.x + v.y * v.y + v.z * v.z + v.w * v.w;
#pragma unroll
  for (int m = 1; m < 64; m <<= 1) s += __shfl_xor(s, m, 64);
  const float inv = 1.0f / fmaxf(sqrtf(s), 1e-12f);
  ushort4 o;
  o.x = f2b(v.x * inv); o.y = f2b(v.y * inv);
  o.z = f2b(v.z * inv); o.w = f2b(v.w * inv);
  const int kb = row >> 5, r = row & 31, g = l >> 1;
  *(ushort4*)(xn + kb * 16384 + r * 512 + ((g ^ (r & 7)) << 4) + ((l & 1) << 3)) = o;
}

// ---------------------------------------------------------------------------
// Prep 2: V^T (bf16), tiled per 32-k block: [kb][16KB tile].
// Tile layout: paired-d rows of 128B: addr = (d>>1)*128 + gg*16 + (k&7)*2
// where gg = ((d&1)*4 + (k_local>>3)) ^ ((d>>1)&7).
__global__ void cn_tr(const float* __restrict__ x, unsigned char* __restrict__ vt) {
  __shared__ __bf16 Lx[64][260];  // +4 pad to spread banks
  const int t = threadIdx.x, rb = blockIdx.x;
#pragma unroll
  for (int it = 0; it < 16; ++it) {
    const int row = it * 4 + (t >> 6);
    const int d = (t & 63) * 4;
    const float4 v = *(const float4*)(x + (rb * 64 + row) * DIMD + d);
    Lx[row][d + 0] = (__bf16)v.x; Lx[row][d + 1] = (__bf16)v.y;
    Lx[row][d + 2] = (__bf16)v.z; Lx[row][d + 3] = (__bf16)v.w;
  }
  __syncthreads();
#pragma unroll
  for (int kh = 0; kh < 2; ++kh) {
#pragma unroll
    for (int it = 0; it < 4; ++it) {
      const int idx = it * 256 + t;
      const int dpair = idx >> 3, gg = idx & 7;
      const int sg = gg ^ (dpair & 7);
      const int d = dpair * 2 + (sg >> 2);
      const int k0 = kh * 32 + (sg & 3) * 8;
      u16 pk[8];
#pragma unroll
      for (int j = 0; j < 8; ++j) {
        union { __bf16 h; u16 u; } c;
        c.h = Lx[k0 + j][d];
        pk[j] = c.u;
      }
      *(uint4*)(vt + (rb * 2 + kh) * 16384 + dpair * 128 + gg * 16) = *(const uint4*)pk;
    }
  }
}

// ---------------------------------------------------------------------------
// Flash kernel: 256 blocks x 512 threads. 8 waves = 4 q-groups (16 rows) x 2
// k-splits. BK=32, double-buffered pair staging (64KB/pair) via
// global_load_lds(16B). mfma_f32_16x16x32_bf16 for QK^T and PV.
// A-layout: row=l&15, k=(l>>4)*8+j. B-layout: col=l&15, k=(l>>4)*8+j.
// C-layout: col=l&15, row=(l>>4)*4+reg (m89-verified).
__global__ __launch_bounds__(512, 2) void cn_flash(
    const float* __restrict__ x,
    const unsigned char* __restrict__ xn,
    const unsigned char* __restrict__ vt,
    float* __restrict__ out) {
  __shared__ __align__(16) unsigned char sK[2][32768];
  __shared__ __align__(16) unsigned char sV[2][32768];
  __shared__ __align__(16) unsigned char sP[8][1024];
  const int tid = threadIdx.x;
  const int w = tid >> 6, l = tid & 63;
  const int qg = w & 3, ks = w >> 2;
  const int b = blockIdx.x;
  const int l15 = l & 15, lg = l >> 4;

  // stage pair 0 (tiles 0,1): 64KB linear copy, 4KB/round K + 4KB/round V
  {
#pragma unroll
    for (int r = 0; r < 4; ++r) {
      const int off = r * 8192 + tid * 16;
      g2l16(xn + off, &sK[0][off]);
      g2l16(vt + off, &sV[0][off]);
    }
  }

  // Q fragments (8 d-chunks of 32) straight from swizzled global
  const int qrow = b * 64 + qg * 16 + l15;
  const int kbq = qrow >> 5, rq = qrow & 31;
  bf16x8 Qf[8];
  {
    const unsigned char* qb = xn + kbq * 16384 + rq * 512;
#pragma unroll
    for (int c = 0; c < 8; ++c)
      Qf[c] = *(const bf16x8*)(qb + (((c * 4 + lg) ^ (rq & 7)) << 4));
  }

  // precomputed LDS byte offsets
  u32 kgo[8];
#pragma unroll
  for (int c = 0; c < 8; ++c) kgo[c] = ((c * 4 + lg) ^ (l & 7)) << 4;
  const u32 krow0 = l15 * 512, krow1 = (16 + l15) * 512;
  u32 voff[16];
#pragma unroll
  for (int dt = 0; dt < 16; ++dt) {
    const int d = dt * 16 + l15;
    voff[dt] = (d >> 1) * 128 + (((((d & 1) << 2) | lg) ^ ((d >> 1) & 7)) << 4);
  }
  const u32 pard = (l15 >> 1) * 128 + (((((l15 & 1) << 2) | lg) ^ ((l15 >> 1) & 7)) << 4);
  u32 pw0[4], pw1[4];
#pragma unroll
  for (int j = 0; j < 4; ++j) {
    const int q = lg * 4 + j;
    const int k0 = l15, k1 = 16 + l15;
    pw0[j] = (q >> 1) * 128 + (((((q & 1) << 2) | (k0 >> 3)) ^ ((q >> 1) & 7)) << 4) + (k0 & 7) * 2;
    pw1[j] = (q >> 1) * 128 + (((((q & 1) << 2) | (k1 >> 3)) ^ ((q >> 1) & 7)) << 4) + (k1 & 7) * 2;
  }

  f32x4 O[16];
#pragma unroll
  for (int dt = 0; dt < 16; ++dt) O[dt] = (f32x4){0.f, 0.f, 0.f, 0.f};
  float mrow[4] = {-INFINITY, -INFINITY, -INFINITY, -INFINITY};
  float lrow[4] = {0.f, 0.f, 0.f, 0.f};

  __syncthreads();

  for (int p = 0; p < 256; ++p) {
    if (p < 255) {  // prefetch next pair (2-phase pipeline)
      const int pb = (p + 1) & 1;
      const unsigned char* gk = xn + (size_t)(p + 1) * 32768;
      const unsigned char* gv = vt + (size_t)(p + 1) * 32768;
#pragma unroll
      for (int r = 0; r < 4; ++r) {
        const int off = r * 8192 + tid * 16;
        g2l16(gk + off, &sK[pb][off]);
        g2l16(gv + off, &sV[pb][off]);
      }
    }
    const unsigned char* Kb = &sK[p & 1][ks * 16384];
    const unsigned char* Vb = &sV[p & 1][ks * 16384];
    unsigned char* Pb = &sP[w][0];

    // ---- QK^T: S[16q][32k], two 16-col tiles
    f32x4 s0 = {0.f, 0.f, 0.f, 0.f}, s1 = {0.f, 0.f, 0.f, 0.f};
#pragma unroll
    for (int c = 0; c < 8; ++c) {
      const bf16x8 b0 = *(const bf16x8*)(Kb + krow0 + kgo[c]);
      const bf16x8 b1 = *(const bf16x8*)(Kb + krow1 + kgo[c]);
      s0 = __builtin_amdgcn_mfma_f32_16x16x32_bf16(Qf[c], b0, s0, 0, 0, 0);
      s1 = __builtin_amdgcn_mfma_f32_16x16x32_bf16(Qf[c], b1, s1, 0, 0, 0);
    }

    // ---- online softmax (defer-max THR=0, exact)
    float tm[4];
    bool need = false;
#pragma unroll
    for (int j = 0; j < 4; ++j) {
      float t = fmaxf(s0[j], s1[j]);
      t = fmaxf(t, __shfl_xor(t, 1, 64));
      t = fmaxf(t, __shfl_xor(t, 2, 64));
      t = fmaxf(t, __shfl_xor(t, 4, 64));
      t = fmaxf(t, __shfl_xor(t, 8, 64));
      tm[j] = t;
      need = need || (t > mrow[j]);
    }
    if (__any(need)) {
      float al[4];
#pragma unroll
      for (int j = 0; j < 4; ++j) {
        const float mn = fmaxf(mrow[j], tm[j]);
        al[j] = __expf(mrow[j] - mn);
        mrow[j] = mn;
        lrow[j] *= al[j];
      }
#pragma unroll
      for (int dt = 0; dt < 16; ++dt) {
        O[dt][0] *= al[0]; O[dt][1] *= al[1];
        O[dt][2] *= al[2]; O[dt][3] *= al[3];
      }
    }
    // P = exp(S - m); lane-partial rowsum; P -> bf16 -> private LDS (transpose)
#pragma unroll
    for (int j = 0; j < 4; ++j) {
      const float p0 = __expf(s0[j] - mrow[j]);
      const float p1 = __expf(s1[j] - mrow[j]);
      lrow[j] += p0 + p1;
      *(u16*)(Pb + pw0[j]) = f2b(p0);
      *(u16*)(Pb + pw1[j]) = f2b(p1);
    }

    // ---- PV: O[16q][256d] += P[16q][32k] @ V[32k][256d]
    const bf16x8 aP = *(const bf16x8*)(Pb + pard);
#pragma unroll
    for (int dt = 0; dt < 16; ++dt) {
      const bf16x8 bV = *(const bf16x8*)(Vb + voff[dt]);
      O[dt] = __builtin_amdgcn_mfma_f32_16x16x32_bf16(aP, bV, O[dt], 0, 0, 0);
    }
    __syncthreads();
  }

  // ---- full rowsum (reduce across the 16-lane group)
#pragma unroll
  for (int j = 0; j < 4; ++j) {
    float t = lrow[j];
    t += __shfl_xor(t, 1, 64);
    t += __shfl_xor(t, 2, 64);
    t += __shfl_xor(t, 4, 64);
    t += __shfl_xor(t, 8, 64);
    lrow[j] = t;
  }

  // ---- k-split merge through now-free sK/sV
  float* base = (qg < 2) ? (float*)&sK[0][0] : (float*)&sV[0][0];
  float* reg = base + (((qg & 1) * 64) + l) * 72;
  if (ks == 1) {
#pragma unroll
    for (int dt = 0; dt < 16; ++dt) *(f32x4*)(reg + dt * 4) = O[dt];
#pragma unroll
    for (int j = 0; j < 4; ++j) { reg[64 + j] = mrow[j]; reg[68 + j] = lrow[j]; }
  }
  __syncthreads();
  if (ks == 0) {
    float a0[4], a1[4], li[4];
#pragma unroll
    for (int j = 0; j < 4; ++j) {
      const float m1 = reg[64 + j], l1 = reg[68 + j];
      const float M = fmaxf(mrow[j], m1);
      a0[j] = __expf(mrow[j] - M);
      a1[j] = __expf(m1 - M);
      li[j] = 1.0f / (a0[j] * lrow[j] + a1[j] * l1);
    }
    const int qb = b * 64 + qg * 16 + lg * 4;
#pragma unroll
    for (int dt = 0; dt < 16; ++dt) {
      const f32x4 o1 = *(const f32x4*)(reg + dt * 4);
      const int d = dt * 16 + l15;
#pragma unroll
      for (int j = 0; j < 4; ++j) {
        const float ov = a0[j] * O[dt][j] + a1[j] * o1[j];
        const int q = qb + j;
        out[q * DIMD + d] = 1.1f * x[q * DIMD + d] - 0.1f * ov * li[j];
      }
    }
  }
}

// ---------------------------------------------------------------------------
extern "C" void kernel_launch(void* const* d_in, const int* in_sizes, int n_in,
                              void* d_out, int out_size, void* d_ws, size_t ws_size,
                              hipStream_t stream) {
  const float* x = (const float*)d_in[0];
  float* out = (float*)d_out;
  unsigned char* xn = (unsigned char*)d_ws;                    // 8 MB tiled bf16 x_norm
  unsigned char* vt = xn + (size_t)8 * 1024 * 1024;            // 8 MB tiled bf16 V^T
  cn_norm<<<4096, 256, 0, stream>>>(x, xn);
  cn_tr<<<256, 256, 0, stream>>>(x, vt);
  cn_flash<<<256, 512, 0, stream>>>(x, xn, vt, out);
}

// Round 2
// 318.008 us; speedup vs baseline: 1.9803x; 1.9803x over previous
//
#include <hip/hip_runtime.h>
#include <stdint.h>

// ContraNorm = 1.1*x - 0.1 * softmax(xn @ xn^T) @ x   (xn = row-L2-normalized x)
// Swapped-operand flash attention, 32x32x16 bf16 MFMA, fixed softmax shift m=1
// (cosine sim <= 1, diagonal = 1 -> exp(s-1) in [e^-2, ~1], exact by shift-invariance).
// N=16384, D=256.

typedef __bf16 bf16x8 __attribute__((ext_vector_type(8)));
typedef float f32x16 __attribute__((ext_vector_type(16)));
typedef unsigned short u16;
typedef unsigned int u32;

#define GLBP __attribute__((address_space(1)))
#define LDSP __attribute__((address_space(3)))

#define NROW 16384
#define DIMD 256

__device__ __forceinline__ void g2l16(const void* g, void* l) {
  __builtin_amdgcn_global_load_lds((const GLBP u32*)g, (LDSP u32*)l, 16, 0, 0);
}

__device__ __forceinline__ u32 cvt_pk(float lo, float hi) {
  u32 r;
  asm("v_cvt_pk_bf16_f32 %0, %1, %2" : "=v"(r) : "v"(lo), "v"(hi));
  return r;
}

__device__ __forceinline__ u16 f2b(float f) {
  union { __bf16 h; u16 u; } cv; cv.h = (__bf16)f; return cv.u;
}

// ---------------------------------------------------------------------------
// Prep 1: row L2-normalize x -> xn (bf16), PRE-PACKED in MFMA fragment order:
// 32-row block rb, frag f (d-chunk of 16), lane lf: 16B granule at
//   rb*16384 + f*1024 + lf*16, holding elem j: row = rb*32+(lf&31),
//   d = f*16 + (lf>>5)*8 + j.   (Serves A-frags for K and B-frags for Q.)
__global__ void cn_norm(const float* __restrict__ x, unsigned char* __restrict__ xn) {
  const int w = threadIdx.x >> 6, l = threadIdx.x & 63;
  const int row = blockIdx.x * 4 + w;
  const float4 v = *(const float4*)(x + row * DIMD + l * 4);
  float s = v.x * v.x + v.y * v.y + v.z * v.z + v.w * v.w;
#pragma unroll
  for (int m = 1; m < 64; m <<= 1) s += __shfl_xor(s, m, 64);
  const float inv = 1.0f / fmaxf(sqrtf(s), 1e-12f);
  ushort4 o;
  o.x = f2b(v.x * inv); o.y = f2b(v.y * inv);
  o.z = f2b(v.z * inv); o.w = f2b(v.w * inv);
  // d = 4l..4l+3: f = l>>2, half = (l>>1)&1, j0 = 4*(l&1)
  const int lf = (((l >> 1) & 1) << 5) + (row & 31);
  *(ushort4*)(xn + (row >> 5) * 16384 + (l >> 2) * 1024 + lf * 16 + ((l & 1) << 3)) = o;
}

// ---------------------------------------------------------------------------
// Prep 2: V^T pre-packed A-frags: per 32-k block kb, frag idx fr = c*2+kh
// (c = d-chunk of 32, kh = 16-k half), lane ln: granule at
//   kb*16384 + fr*1024 + ln*16, elem j: V[kb*32 + kh*16 + (ln>>5)*8 + j][c*32 + (ln&31)]
__global__ void cn_vtpack(const float* __restrict__ x, unsigned char* __restrict__ vt) {
  __shared__ u16 Lx[32][264];  // pad: bank rotates by 4 per k-row
  const int t = threadIdx.x, kb = blockIdx.x;
  {
    const int row = t >> 3, d0 = (t & 7) * 32;
    const float* src = x + (size_t)(kb * 32 + row) * DIMD + d0;
#pragma unroll
    for (int i = 0; i < 8; ++i) {
      const float4 v = *(const float4*)(src + i * 4);
      Lx[row][d0 + i * 4 + 0] = f2b(v.x);
      Lx[row][d0 + i * 4 + 1] = f2b(v.y);
      Lx[row][d0 + i * 4 + 2] = f2b(v.z);
      Lx[row][d0 + i * 4 + 3] = f2b(v.w);
    }
  }
  __syncthreads();
#pragma unroll
  for (int gi = 0; gi < 4; ++gi) {
    const int G = gi * 256 + t;
    const int fr = G >> 6, ln = G & 63;
    const int d = (fr >> 1) * 32 + (ln & 31);
    const int k0 = (fr & 1) * 16 + (ln >> 5) * 8;
    u16 pk[8];
#pragma unroll
    for (int j = 0; j < 8; ++j) pk[j] = Lx[k0 + j][d];
    *(uint4*)(vt + kb * 16384 + fr * 1024 + ln * 16) = *(const uint4*)pk;
  }
}

// ---------------------------------------------------------------------------
// Flash kernel. Block = 4 waves x 32 q-rows = 128 q. Grid = 128 * NS blocks,
// split = bid & (NS-1)  (XCD i then serves exactly one k-split stream -> its
// 4MB working set is L2-resident). BK=32, double-buffered linear LDS staging
// via global_load_lds(16B); all ds_read_b128 linear (conflict-free).
// Swapped MFMAs: St[k][q] = K.Q^T (A=K frag, B=Q regs); O^T[d][q] += V^T.P^T.
// C-layout (m101): col = l&31 (=q), row = (r&3)+8*(r>>2)+4*(l>>5).
template <int NS, bool DIRECT>
__global__ __launch_bounds__(256, 2) void cn_flash(
    const unsigned char* __restrict__ xn,
    const unsigned char* __restrict__ vt,
    unsigned char* __restrict__ Po,   // bf16 [NS][256][16384]
    float* __restrict__ Ls,           // f32 [NS][2][16384]
    const float* __restrict__ x,      // DIRECT only
    float* __restrict__ out) {        // DIRECT only
  constexpr int SH = (NS == 4) ? 2 : (NS == 2) ? 1 : 0;
  constexpr int KT = NROW / (32 * NS);
  __shared__ __align__(16) unsigned char sK[2][16384];
  __shared__ __align__(16) unsigned char sV[2][16384];
  const int tid = threadIdx.x;
  const int w = tid >> 6, l = tid & 63;
  const int bid = blockIdx.x;
  const int split = bid & (NS - 1), qblk = bid >> SH;
  const int q0 = qblk * 128 + w * 32;
  const int lq = l & 31, hi = l >> 5;

  const size_t gbase = (size_t)split * KT * 16384;
  // prologue: stage tile 0
#pragma unroll
  for (int r = 0; r < 4; ++r) {
    g2l16(xn + gbase + r * 4096 + tid * 16, &sK[0][r * 4096 + tid * 16]);
    g2l16(vt + gbase + r * 4096 + tid * 16, &sV[0][r * 4096 + tid * 16]);
  }
  // Q fragments (B-operand, n = q = l&31, k-chunk = (l>>5)*8+j), 64 VGPR
  bf16x8 Qf[16];
  {
    const unsigned char* qb = xn + (size_t)(q0 >> 5) * 16384;
#pragma unroll
    for (int f = 0; f < 16; ++f) Qf[f] = *(const bf16x8*)(qb + f * 1024 + l * 16);
  }

  f32x16 O[8];
#pragma unroll
  for (int c = 0; c < 8; ++c)
#pragma unroll
    for (int r = 0; r < 16; ++r) O[c][r] = 0.f;
  float lsum = 0.f;

  __syncthreads();

  for (int t = 0; t < KT; ++t) {
    const int cur = t & 1;
    if (t + 1 < KT) {  // prefetch next tile into other buffer
      const size_t gt = gbase + (size_t)(t + 1) * 16384;
      const int nb = cur ^ 1;
#pragma unroll
      for (int r = 0; r < 4; ++r) {
        g2l16(xn + gt + r * 4096 + tid * 16, &sK[nb][r * 4096 + tid * 16]);
        g2l16(vt + gt + r * 4096 + tid * 16, &sV[nb][r * 4096 + tid * 16]);
      }
    }
    const unsigned char* Kb = &sK[cur][0];
    const unsigned char* Vb = &sV[cur][0];

    // ---- St[32k][32q] = K . Q^T over d=256 (16 frags)
    f32x16 St;
#pragma unroll
    for (int r = 0; r < 16; ++r) St[r] = 0.f;
#pragma unroll
    for (int f = 0; f < 16; ++f) {
      const bf16x8 ka = *(const bf16x8*)(Kb + f * 1024 + l * 16);
      St = __builtin_amdgcn_mfma_f32_32x32x16_bf16(ka, Qf[f], St, 0, 0, 0);
    }

    // ---- p = exp(s - 1)  (fixed shift; exact), lane-local rowsum
    float p[16];
#pragma unroll
    for (int r = 0; r < 16; ++r) {
      p[r] = __expf(St[r] - 1.0f);
      lsum += p[r];
    }
    // ---- pack P^T B-frags: cvt_pk + permlane32_swap (no LDS)
    u32 a0 = cvt_pk(p[0], p[1]), a1 = cvt_pk(p[2], p[3]);
    u32 b0 = cvt_pk(p[4], p[5]), b1 = cvt_pk(p[6], p[7]);
    asm("v_permlane32_swap_b32 %0, %1" : "+v"(a0), "+v"(b0));
    asm("v_permlane32_swap_b32 %0, %1" : "+v"(a1), "+v"(b1));
    u32 c0 = cvt_pk(p[8], p[9]), c1 = cvt_pk(p[10], p[11]);
    u32 d0 = cvt_pk(p[12], p[13]), d1 = cvt_pk(p[14], p[15]);
    asm("v_permlane32_swap_b32 %0, %1" : "+v"(c0), "+v"(d0));
    asm("v_permlane32_swap_b32 %0, %1" : "+v"(c1), "+v"(d1));
    union PW { u32 w[4]; bf16x8 v; } pf0, pf1;
    pf0.w[0] = a0; pf0.w[1] = a1; pf0.w[2] = b0; pf0.w[3] = b1;
    pf1.w[0] = c0; pf1.w[1] = c1; pf1.w[2] = d0; pf1.w[3] = d1;

    // ---- O^T[d][q] += V^T . P^T  (8 d-chunks x 2 k-halves)
#pragma unroll
    for (int c = 0; c < 8; ++c) {
      const bf16x8 va0 = *(const bf16x8*)(Vb + (c * 2 + 0) * 1024 + l * 16);
      O[c] = __builtin_amdgcn_mfma_f32_32x32x16_bf16(va0, pf0.v, O[c], 0, 0, 0);
      const bf16x8 va1 = *(const bf16x8*)(Vb + (c * 2 + 1) * 1024 + l * 16);
      O[c] = __builtin_amdgcn_mfma_f32_32x32x16_bf16(va1, pf1.v, O[c], 0, 0, 0);
    }
    __syncthreads();
  }

  // ---- epilogue
  const int qc = q0 + lq;
  if (DIRECT) {
    const float Lt = lsum + __shfl_xor(lsum, 32, 64);
    const float sc = 0.1f / Lt;
#pragma unroll
    for (int c = 0; c < 8; ++c)
#pragma unroll
      for (int r = 0; r < 16; ++r) {
        const int d = c * 32 + (r & 3) + 8 * (r >> 2) + 4 * hi;
        out[(size_t)qc * DIMD + d] =
            1.1f * x[(size_t)qc * DIMD + d] - sc * O[c][r];
      }
  } else {
#pragma unroll
    for (int c = 0; c < 8; ++c)
#pragma unroll
      for (int r = 0; r < 16; ++r) {
        const int d = c * 32 + (r & 3) + 8 * (r >> 2) + 4 * hi;
        *(u16*)(Po + ((size_t)split * DIMD + d) * 32768 + (size_t)qc * 2) = f2b(O[c][r]);
      }
    Ls[(size_t)(split * 2 + hi) * NROW + qc] = lsum;
  }
}

// ---------------------------------------------------------------------------
// Merge: out[q][d] = 1.1 x - 0.1 * (sum_s Po[s][d][q]) / (sum_s,h Ls[s][h][q])
// Block: 64 q x 256 d, LDS transpose. Po reads fully coalesced (128B rows).
template <int NS>
__global__ void cn_merge(const float* __restrict__ x,
                         const unsigned char* __restrict__ Po,
                         const float* __restrict__ Ls,
                         float* __restrict__ out) {
  __shared__ float acc[256][65];
  __shared__ float Lq[64];
  const int t = threadIdx.x;
  const int q0 = blockIdx.x * 64;
  const int dloc = t >> 3, ch = t & 7;
#pragma unroll
  for (int pass = 0; pass < 8; ++pass) {
    const int d = pass * 32 + dloc;
    float a[8] = {0.f, 0.f, 0.f, 0.f, 0.f, 0.f, 0.f, 0.f};
#pragma unroll
    for (int s = 0; s < NS; ++s) {
      const uint4 v = *(const uint4*)(Po + ((size_t)(s * 256 + d)) * 32768 +
                                      (size_t)q0 * 2 + ch * 16);
      const u32 wv[4] = {v.x, v.y, v.z, v.w};
#pragma unroll
      for (int k = 0; k < 4; ++k) {
        a[2 * k + 0] += __uint_as_float(wv[k] << 16);
        a[2 * k + 1] += __uint_as_float(wv[k] & 0xffff0000u);
      }
    }
#pragma unroll
    for (int j = 0; j < 8; ++j) acc[d][ch * 8 + j] = a[j];
  }
  if (t < 64) {
    const int q = q0 + t;
    float L = 0.f;
#pragma unroll
    for (int s = 0; s < NS; ++s)
      L += Ls[(size_t)(s * 2 + 0) * NROW + q] + Ls[(size_t)(s * 2 + 1) * NROW + q];
    Lq[t] = 1.0f / L;
  }
  __syncthreads();
  const int ql = t >> 2, dd0 = (t & 3) * 64;
  const float inv = Lq[ql];
  const int q = q0 + ql;
#pragma unroll
  for (int i = 0; i < 64; i += 4) {
    const float4 xv = *(const float4*)(x + (size_t)q * DIMD + dd0 + i);
    float4 ov;
    ov.x = 1.1f * xv.x - 0.1f * acc[dd0 + i + 0][ql] * inv;
    ov.y = 1.1f * xv.y - 0.1f * acc[dd0 + i + 1][ql] * inv;
    ov.z = 1.1f * xv.z - 0.1f * acc[dd0 + i + 2][ql] * inv;
    ov.w = 1.1f * xv.w - 0.1f * acc[dd0 + i + 3][ql] * inv;
    *(float4*)(out + (size_t)q * DIMD + dd0 + i) = ov;
  }
}

// ---------------------------------------------------------------------------
extern "C" void kernel_launch(void* const* d_in, const int* in_sizes, int n_in,
                              void* d_out, int out_size, void* d_ws, size_t ws_size,
                              hipStream_t stream) {
  const float* x = (const float*)d_in[0];
  float* out = (float*)d_out;
  unsigned char* xn = (unsigned char*)d_ws;                      // 8 MB packed bf16 x_norm
  unsigned char* vt = xn + (size_t)8 * 1024 * 1024;              // 8 MB packed bf16 V^T
  unsigned char* Po = vt + (size_t)8 * 1024 * 1024;              // NS * 8 MB bf16 partials

  cn_norm<<<4096, 256, 0, stream>>>(x, xn);
  cn_vtpack<<<512, 256, 0, stream>>>(x, vt);

  const size_t need4 = (size_t)(16 + 32) * 1024 * 1024 + 512 * 1024;
  const size_t need2 = (size_t)(16 + 16) * 1024 * 1024 + 256 * 1024;
  if (ws_size >= need4) {
    float* Ls = (float*)(Po + (size_t)4 * 8 * 1024 * 1024);
    cn_flash<4, false><<<512, 256, 0, stream>>>(xn, vt, Po, Ls, x, out);
    cn_merge<4><<<256, 256, 0, stream>>>(x, Po, Ls, out);
  } else if (ws_size >= need2) {
    float* Ls = (float*)(Po + (size_t)2 * 8 * 1024 * 1024);
    cn_flash<2, false><<<256, 256, 0, stream>>>(xn, vt, Po, Ls, x, out);
    cn_merge<2><<<256, 256, 0, stream>>>(x, Po, Ls, out);
  } else {
    cn_flash<1, true><<<128, 256, 0, stream>>>(xn, vt, nullptr, nullptr, x, out);
  }
}